// Round 1
// baseline (74.910 us; speedup 1.0000x reference)
//
#include <hip/hip_runtime.h>
#include <hip/hip_bf16.h>

#define N_SAMPLES 4096
#define DIM 512
#define BM 128
#define BN 128
#define BK 64

typedef __attribute__((ext_vector_type(8))) short short8;
typedef __attribute__((ext_vector_type(4))) float floatx4;

__device__ __forceinline__ void gload_lds16(const void* gptr, void* lptr) {
    __builtin_amdgcn_global_load_lds(
        (const __attribute__((address_space(1))) void*)gptr,
        (__attribute__((address_space(3))) void*)lptr, 16, 0, 0);
}

// ---------------------------------------------------------------------------
// Kernel 1: row L2-normalize fp32 features -> bf16 G (4096 x 512)
// sim = dot(f_i,f_j)/max(n_i*n_j, 1e-8); norms ~22 >> eps, so g = f/n is exact
// to the reference math up to fp32 rounding.
// ---------------------------------------------------------------------------
__global__ __launch_bounds__(256) void scl_normalize(
    const float* __restrict__ F, __hip_bfloat16* __restrict__ G)
{
    const int row = blockIdx.x;
    const int t = threadIdx.x;
    const float* fr = F + (size_t)row * DIM;
    float2 v = ((const float2*)fr)[t];          // 2 elems/thread, 256 thr = 512
    float ss = v.x * v.x + v.y * v.y;
    #pragma unroll
    for (int off = 1; off < 64; off <<= 1) ss += __shfl_xor(ss, off);
    __shared__ float wsum[4];
    if ((t & 63) == 0) wsum[t >> 6] = ss;
    __syncthreads();
    float tot = wsum[0] + wsum[1] + wsum[2] + wsum[3];
    float inv = tot > 0.f ? 1.0f / sqrtf(tot) : 0.f;
    __hip_bfloat162 h;
    h.x = __float2bfloat16(v.x * inv);
    h.y = __float2bfloat16(v.y * inv);
    ((__hip_bfloat162*)(G + (size_t)row * DIM))[t] = h;
}

// ---------------------------------------------------------------------------
// Kernel 2: S = G*G^T tile (128x128, BK=64), bf16 MFMA 16x16x32, fused epilogue:
//   row_sum[i] += sum_j!=i exp(10*s_ij)
//   pos_sum[i] += sum_{j: lbl_j==lbl_i, j!=i} exp(10*s_ij)
// 4 waves (2x2), each computes a 64x64 sub-tile as 4x4 fragments.
// ---------------------------------------------------------------------------
__global__ __launch_bounds__(256) void scl_gemm_epilogue(
    const __hip_bfloat16* __restrict__ G,
    const int* __restrict__ labels,
    float* __restrict__ row_sum,
    float* __restrict__ pos_sum)
{
    __shared__ __hip_bfloat16 As[BM * BK];
    __shared__ __hip_bfloat16 Bs[BN * BK];

    const int t = threadIdx.x;
    const int lane = t & 63;
    const int wid = t >> 6;
    const int wr = wid >> 1;            // wave row 0..1 (64 rows each)
    const int wc = wid & 1;             // wave col 0..1 (64 cols each)
    const int brow = blockIdx.y * BM;
    const int bcol = blockIdx.x * BN;

    floatx4 acc[4][4];
    #pragma unroll
    for (int m = 0; m < 4; m++)
        #pragma unroll
        for (int n = 0; n < 4; n++)
            acc[m][n] = (floatx4)0.f;

    const short* Gs = (const short*)G;

    for (int k0 = 0; k0 < DIM; k0 += BK) {
        // stage A (rows brow..+127) and B (rows bcol..+127), k0..k0+63, 16B/lane
        #pragma unroll
        for (int r = 0; r < 4; r++) {
            int idx = r * 256 + t;              // 16B chunk index, 0..1023
            int arow = idx >> 3;                // row 0..127
            int ac8  = idx & 7;                 // which 8-bf16 chunk in row
            gload_lds16(Gs + (size_t)(brow + arow) * DIM + k0 + ac8 * 8,
                        (short*)As + idx * 8);
            gload_lds16(Gs + (size_t)(bcol + arow) * DIM + k0 + ac8 * 8,
                        (short*)Bs + idx * 8);
        }
        __syncthreads();

        #pragma unroll
        for (int kk = 0; kk < 2; kk++) {
            short8 a[4], b[4];
            #pragma unroll
            for (int m = 0; m < 4; m++)
                a[m] = *(const short8*)((const short*)As +
                        ((wr * 64 + m * 16 + (lane & 15)) * BK + kk * 32 + (lane >> 4) * 8));
            #pragma unroll
            for (int n = 0; n < 4; n++)
                b[n] = *(const short8*)((const short*)Bs +
                        ((wc * 64 + n * 16 + (lane & 15)) * BK + kk * 32 + (lane >> 4) * 8));
            #pragma unroll
            for (int m = 0; m < 4; m++)
                #pragma unroll
                for (int n = 0; n < 4; n++)
                    acc[m][n] = __builtin_amdgcn_mfma_f32_16x16x32_bf16(
                        a[m], b[n], acc[m][n], 0, 0, 0);
        }
        __syncthreads();
    }

    // ---- epilogue: exp + masked row reductions ----
    // C/D layout (m89-verified): col = lane&15, row = (lane>>4)*4 + reg
    const int colbase = bcol + wc * 64 + (lane & 15);
    int lc[4];
    #pragma unroll
    for (int n = 0; n < 4; n++) lc[n] = labels[colbase + n * 16];

    #pragma unroll
    for (int m = 0; m < 4; m++) {
        #pragma unroll
        for (int j = 0; j < 4; j++) {
            const int i = brow + wr * 64 + m * 16 + (lane >> 4) * 4 + j;
            const int li = labels[i];
            float pr = 0.f, pp = 0.f;
            #pragma unroll
            for (int n = 0; n < 4; n++) {
                float s = acc[m][n][j];
                int jc = colbase + n * 16;
                float e = __expf(10.0f * s);
                bool diag = (i == jc);
                pr += diag ? 0.f : e;                      // exp(-1e10) = 0
                pp += (!diag && (li == lc[n])) ? e : 0.f;  // positives only
            }
            // reduce across the 16 lanes covering 16 cols of row i
            #pragma unroll
            for (int off = 1; off < 16; off <<= 1) {
                pr += __shfl_xor(pr, off);
                pp += __shfl_xor(pp, off);
            }
            if ((lane & 15) == 0) {
                atomicAdd(&row_sum[i], pr);
                atomicAdd(&pos_sum[i], pp);
            }
        }
    }
}

// ---------------------------------------------------------------------------
// Kernel 3: finalize.
//   cnt_j = hist[label_j]-1;  pos_total_j = pos_sum[j] + (N - cnt_j)
//   A = sum_i -log(row_sum_i); B = sum_j 1/cnt_j; C = sum_j log(pos_total+1e-9)/cnt_j
//   out = -(A*B + N*C)/N^2     (double accumulation: cancellation A*B vs N*C)
// ---------------------------------------------------------------------------
__global__ __launch_bounds__(256) void scl_finalize(
    const int* __restrict__ labels,
    const float* __restrict__ row_sum,
    const float* __restrict__ pos_sum,
    float* __restrict__ out)
{
    __shared__ int hist[16];
    __shared__ double red[3][4];
    const int t = threadIdx.x;
    if (t < 16) hist[t] = 0;
    __syncthreads();
    for (int i = t; i < N_SAMPLES; i += 256)
        atomicAdd(&hist[labels[i] & 15], 1);
    __syncthreads();

    double a = 0.0, b = 0.0, c = 0.0;
    for (int i = t; i < N_SAMPLES; i += 256) {
        int cnt = hist[labels[i] & 15] - 1;
        a -= log((double)row_sum[i]);
        double ps = (double)pos_sum[i] + (double)(N_SAMPLES - cnt);
        double inv = 1.0 / (double)cnt;
        b += inv;
        c += log(ps + 1e-9) * inv;
    }
    #pragma unroll
    for (int off = 1; off < 64; off <<= 1) {
        a += __shfl_xor(a, off);
        b += __shfl_xor(b, off);
        c += __shfl_xor(c, off);
    }
    if ((t & 63) == 0) { red[0][t >> 6] = a; red[1][t >> 6] = b; red[2][t >> 6] = c; }
    __syncthreads();
    if (t == 0) {
        double A = red[0][0] + red[0][1] + red[0][2] + red[0][3];
        double B = red[1][0] + red[1][1] + red[1][2] + red[1][3];
        double C = red[2][0] + red[2][1] + red[2][2] + red[2][3];
        double res = -(A * B + (double)N_SAMPLES * C) /
                     ((double)N_SAMPLES * (double)N_SAMPLES);
        out[0] = (float)res;
    }
}

// ---------------------------------------------------------------------------
extern "C" void kernel_launch(void* const* d_in, const int* in_sizes, int n_in,
                              void* d_out, int out_size, void* d_ws, size_t ws_size,
                              hipStream_t stream)
{
    const float* F = (const float*)d_in[0];
    const int* labels = (const int*)d_in[1];
    float* out = (float*)d_out;

    char* ws = (char*)d_ws;
    __hip_bfloat16* G = (__hip_bfloat16*)ws;                        // 4 MB
    float* row_sum = (float*)(ws + (size_t)N_SAMPLES * DIM * 2);    // 16 KB
    float* pos_sum = row_sum + N_SAMPLES;                           // 16 KB

    hipMemsetAsync(row_sum, 0, 2 * N_SAMPLES * sizeof(float), stream);
    scl_normalize<<<N_SAMPLES, 256, 0, stream>>>(F, G);
    dim3 grid(N_SAMPLES / BN, N_SAMPLES / BM);
    scl_gemm_epilogue<<<grid, 256, 0, stream>>>(G, labels, row_sum, pos_sum);
    scl_finalize<<<1, 256, 0, stream>>>(labels, row_sum, pos_sum, out);
}

// Round 2
// 54.069 us; speedup vs baseline: 1.3854x; 1.3854x over previous
//
#include <hip/hip_runtime.h>
#include <hip/hip_bf16.h>

#define N_SAMPLES 4096
#define DIM 512
#define BM 128
#define BK 64
#define NK (DIM / BK)                 // 8 K-steps
#define NBT (N_SAMPLES / BM)          // 32 tiles per dim
#define NTILES (NBT * (NBT + 1) / 2)  // 528 upper-triangle tiles

typedef __attribute__((ext_vector_type(8))) short short8;
typedef __attribute__((ext_vector_type(4))) float floatx4;

__device__ __forceinline__ void gload_lds16(const void* gptr, void* lptr) {
    __builtin_amdgcn_global_load_lds(
        (const __attribute__((address_space(1))) void*)gptr,
        (__attribute__((address_space(3))) void*)lptr, 16, 0, 0);
}

// ---------------------------------------------------------------------------
// Kernel 1: row L2-normalize fp32 features -> bf16 G; also zero the
// row_sum/pos_sum accumulators (replaces a memset dispatch).
// ---------------------------------------------------------------------------
__global__ __launch_bounds__(256) void scl_normalize(
    const float* __restrict__ F, __hip_bfloat16* __restrict__ G,
    float* __restrict__ row_sum, float* __restrict__ pos_sum)
{
    const int row = blockIdx.x;
    const int t = threadIdx.x;
    const float* fr = F + (size_t)row * DIM;
    float2 v = ((const float2*)fr)[t];          // 2 elems/thread
    float ss = v.x * v.x + v.y * v.y;
    #pragma unroll
    for (int off = 1; off < 64; off <<= 1) ss += __shfl_xor(ss, off);
    __shared__ float wsum[4];
    if ((t & 63) == 0) wsum[t >> 6] = ss;
    __syncthreads();
    float tot = wsum[0] + wsum[1] + wsum[2] + wsum[3];
    float inv = tot > 0.f ? 1.0f / sqrtf(tot) : 0.f;
    __hip_bfloat162 h;
    h.x = __float2bfloat16(v.x * inv);
    h.y = __float2bfloat16(v.y * inv);
    ((__hip_bfloat162*)(G + (size_t)row * DIM))[t] = h;
    if (t == 0) { row_sum[row] = 0.f; pos_sum[row] = 0.f; }
}

// ---------------------------------------------------------------------------
// Kernel 2: upper-triangle tile (bi<=bj) of S = G*G^T, bf16 MFMA 16x16x32.
// LDS XOR-swizzled (rule #21: linear gload_lds dest + XOR'd global source
// chunk + XOR'd ds_read) -> 16-way bank conflict becomes free 2-way.
// Double-buffered, prefetch issued before compute.
// Epilogue: row sums always; column sums too for off-diagonal tiles
// (S symmetric -> col sums are the transposed tile's row sums).
// ---------------------------------------------------------------------------
__global__ __launch_bounds__(256) void scl_gemm_epilogue(
    const __hip_bfloat16* __restrict__ G,
    const int* __restrict__ labels,
    float* __restrict__ row_sum,
    float* __restrict__ pos_sum)
{
    __shared__ short As[2][BM * BK];
    __shared__ short Bs[2][BM * BK];

    const int t = threadIdx.x;
    const int lane = t & 63;
    const int q = lane >> 4;            // quarter-group 0..3
    const int wid = t >> 6;
    const int wr = wid >> 1;            // wave row 0..1
    const int wc = wid & 1;             // wave col 0..1

    // triangular decode: blockIdx.x -> (bi <= bj)
    int b = blockIdx.x;
    int bi = (int)((65.0f - sqrtf(4225.0f - 8.0f * (float)b)) * 0.5f);
    while (32 * bi - bi * (bi - 1) / 2 > b) --bi;
    while (32 * (bi + 1) - (bi + 1) * bi / 2 <= b) ++bi;
    const int bj = bi + (b - (32 * bi - bi * (bi - 1) / 2));
    const int brow = bi * BM;
    const int bcol = bj * BM;
    const bool isdiag = (bi == bj);

    const short* Gs = (const short*)G;

    floatx4 acc[4][4];
    #pragma unroll
    for (int m = 0; m < 4; m++)
        #pragma unroll
        for (int n = 0; n < 4; n++)
            acc[m][n] = (floatx4)0.f;

    // stage one K-tile into buffer `buf`; source chunk XOR'd so that a
    // swizzled ds_read returns the linear data (XOR is an involution).
    auto stage = [&](int buf, int k0) {
        #pragma unroll
        for (int r = 0; r < 4; r++) {
            int idx = r * 256 + t;              // 16B chunk id, 0..1023
            int row = idx >> 3;                 // tile row 0..127
            int cg = (idx & 7) ^ (row & 7);     // swizzled k-chunk
            gload_lds16(Gs + (size_t)(brow + row) * DIM + k0 + cg * 8,
                        As[buf] + idx * 8);
            if (!isdiag)
                gload_lds16(Gs + (size_t)(bcol + row) * DIM + k0 + cg * 8,
                            Bs[buf] + idx * 8);
        }
    };

    stage(0, 0);
    __syncthreads();
    int cur = 0;
    for (int kt = 0; kt < NK; ++kt) {
        if (kt + 1 < NK) stage(cur ^ 1, (kt + 1) * BK);   // prefetch in flight
        const short* Ab = As[cur];
        const short* Bb = isdiag ? As[cur] : Bs[cur];
        #pragma unroll
        for (int kk = 0; kk < 2; kk++) {
            short8 a[4], bfr[4];
            #pragma unroll
            for (int m = 0; m < 4; m++) {
                int row = wr * 64 + m * 16 + (lane & 15);
                a[m] = *(const short8*)(Ab + row * BK +
                        (((kk * 4 + q) ^ (row & 7)) * 8));
            }
            #pragma unroll
            for (int n = 0; n < 4; n++) {
                int row = wc * 64 + n * 16 + (lane & 15);
                bfr[n] = *(const short8*)(Bb + row * BK +
                        (((kk * 4 + q) ^ (row & 7)) * 8));
            }
            #pragma unroll
            for (int m = 0; m < 4; m++)
                #pragma unroll
                for (int n = 0; n < 4; n++)
                    acc[m][n] = __builtin_amdgcn_mfma_f32_16x16x32_bf16(
                        a[m], bfr[n], acc[m][n], 0, 0, 0);
        }
        __syncthreads();   // drains prefetch vmcnt (had whole compute to fly)
        cur ^= 1;
    }

    // ---- epilogue ----
    // C/D layout: col = lane&15, row = q*4 + reg (m89-verified)
    const int colbase = bcol + wc * 64 + (lane & 15);
    int lc[4];
    #pragma unroll
    for (int n = 0; n < 4; n++) lc[n] = labels[colbase + n * 16];

    float pcr[4] = {0.f, 0.f, 0.f, 0.f};   // column partials (row_sum of S^T)
    float pcp[4] = {0.f, 0.f, 0.f, 0.f};

    #pragma unroll
    for (int m = 0; m < 4; m++) {
        #pragma unroll
        for (int j = 0; j < 4; j++) {
            const int i = brow + wr * 64 + m * 16 + q * 4 + j;
            const int li = labels[i];
            float pr = 0.f, pp = 0.f;
            #pragma unroll
            for (int n = 0; n < 4; n++) {
                float e = __expf(10.0f * acc[m][n][j]);
                bool dg = (i == colbase + n * 16);     // only true on diag tiles
                bool pos = (li == lc[n]) && !dg;
                float er = dg ? 0.f : e;
                float ep = pos ? e : 0.f;
                pr += er;
                pp += ep;
                pcr[n] += er;
                pcp[n] += ep;
            }
            #pragma unroll
            for (int off = 1; off < 16; off <<= 1) {
                pr += __shfl_xor(pr, off);
                pp += __shfl_xor(pp, off);
            }
            if ((lane & 15) == 0) {
                atomicAdd(&row_sum[i], pr);
                atomicAdd(&pos_sum[i], pp);
            }
        }
    }

    if (!isdiag) {
        #pragma unroll
        for (int n = 0; n < 4; n++) {
            pcr[n] += __shfl_xor(pcr[n], 16);
            pcr[n] += __shfl_xor(pcr[n], 32);
            pcp[n] += __shfl_xor(pcp[n], 16);
            pcp[n] += __shfl_xor(pcp[n], 32);
        }
        if (lane < 16) {
            #pragma unroll
            for (int n = 0; n < 4; n++) {
                atomicAdd(&row_sum[colbase + n * 16], pcr[n]);
                atomicAdd(&pos_sum[colbase + n * 16], pcp[n]);
            }
        }
    }
}

// ---------------------------------------------------------------------------
// Kernel 3: finalize (float __logf; final combination in double).
// ---------------------------------------------------------------------------
__global__ __launch_bounds__(256) void scl_finalize(
    const int* __restrict__ labels,
    const float* __restrict__ row_sum,
    const float* __restrict__ pos_sum,
    float* __restrict__ out)
{
    __shared__ int hist[16];
    __shared__ double red[3][4];
    const int t = threadIdx.x;
    if (t < 16) hist[t] = 0;
    __syncthreads();
    for (int i = t; i < N_SAMPLES; i += 256)
        atomicAdd(&hist[labels[i] & 15], 1);
    __syncthreads();

    double a = 0.0, b = 0.0, c = 0.0;
    for (int i = t; i < N_SAMPLES; i += 256) {
        int cnt = hist[labels[i] & 15] - 1;
        a -= (double)__logf(row_sum[i]);
        float ps = pos_sum[i] + (float)(N_SAMPLES - cnt);
        double inv = 1.0 / (double)cnt;
        b += inv;
        c += (double)__logf(ps) * inv;
    }
    #pragma unroll
    for (int off = 1; off < 64; off <<= 1) {
        a += __shfl_xor(a, off);
        b += __shfl_xor(b, off);
        c += __shfl_xor(c, off);
    }
    if ((t & 63) == 0) { red[0][t >> 6] = a; red[1][t >> 6] = b; red[2][t >> 6] = c; }
    __syncthreads();
    if (t == 0) {
        double A = red[0][0] + red[0][1] + red[0][2] + red[0][3];
        double B = red[1][0] + red[1][1] + red[1][2] + red[1][3];
        double C = red[2][0] + red[2][1] + red[2][2] + red[2][3];
        double res = -(A * B + (double)N_SAMPLES * C) /
                     ((double)N_SAMPLES * (double)N_SAMPLES);
        out[0] = (float)res;
    }
}

// ---------------------------------------------------------------------------
extern "C" void kernel_launch(void* const* d_in, const int* in_sizes, int n_in,
                              void* d_out, int out_size, void* d_ws, size_t ws_size,
                              hipStream_t stream)
{
    const float* F = (const float*)d_in[0];
    const int* labels = (const int*)d_in[1];
    float* out = (float*)d_out;

    char* ws = (char*)d_ws;
    __hip_bfloat16* G = (__hip_bfloat16*)ws;                        // 4 MB
    float* row_sum = (float*)(ws + (size_t)N_SAMPLES * DIM * 2);
    float* pos_sum = row_sum + N_SAMPLES;

    scl_normalize<<<N_SAMPLES, 256, 0, stream>>>(F, G, row_sum, pos_sum);
    scl_gemm_epilogue<<<NTILES, 256, 0, stream>>>(G, labels, row_sum, pos_sum);
    scl_finalize<<<1, 256, 0, stream>>>(labels, row_sum, pos_sum, out);
}